// Round 2
// baseline (92264.844 us; speedup 1.0000x reference)
//
#include <hip/hip_runtime.h>
#include <math.h>

typedef unsigned int u32;

#define T_     1024
#define N_     128
#define V_     35
#define H_     512
#define VS_    128
#define KS_    128
#define MAXLEN 250
#define NBLK   256
#define ASTR   1152   // A row: [emb(512) | vm(128) | h1(512)]

// ---- workspace layout (bytes) ----
#define OFF_A0  256
#define SZ_A    (N_*ASTR*4)          // 589824
#define OFF_A1  (OFF_A0+SZ_A)
#define OFF_C1  (OFF_A1+SZ_A)
#define SZ_C1   (N_*H_*4)            // 262144
#define OFF_H2A (OFF_C1+SZ_C1)
#define SZ_H2   (N_*KS_*4)           // 65536
#define OFF_H2B (OFF_H2A+SZ_H2)
#define OFF_C2  (OFF_H2B+SZ_H2)
// total ~1.64 MB

__device__ __forceinline__ float sigf(float x){ return 1.0f/(1.0f+expf(-x)); }
__device__ __forceinline__ float dot4(float4 a, float4 b){ return a.x*b.x + a.y*b.y + a.z*b.z + a.w*b.w; }

// monotonic-epoch grid barrier. cnt/flag zeroed by hipMemsetAsync before launch.
__device__ __forceinline__ void gbar(u32* cnt, u32* flag, u32 ep){
  __syncthreads();
  if (threadIdx.x == 0){
    u32 prev = __hip_atomic_fetch_add(cnt, 1u, __ATOMIC_ACQ_REL, __HIP_MEMORY_SCOPE_AGENT);
    if (prev == ep*NBLK - 1u){
      __hip_atomic_store(flag, ep, __ATOMIC_RELEASE, __HIP_MEMORY_SCOPE_AGENT);
    } else {
      while (__hip_atomic_load(flag, __ATOMIC_ACQUIRE, __HIP_MEMORY_SCOPE_AGENT) < ep)
        __builtin_amdgcn_s_sleep(1);
    }
  }
  __syncthreads();
}

// ---- one-time prep: values_mean, A0 init (emb[0] | vm | 0), zero c1/c2/h2a ----
__global__ void prep_state(const float* __restrict__ val, const float* __restrict__ emb, char* __restrict__ ws){
  float* A0  = (float*)(ws + OFF_A0);
  float* A1  = (float*)(ws + OFF_A1);
  float* C1  = (float*)(ws + OFF_C1);
  float* H2A = (float*)(ws + OFF_H2A);
  float* C2  = (float*)(ws + OFF_C2);
  int i = blockIdx.x*256 + threadIdx.x;
  if (i < 16384){                       // values_mean -> both A buffers
    int n = i >> 7, v = i & 127;
    float acc = 0.f;
    for (int t = 0; t < T_; ++t) acc += val[((size_t)t*N_ + n)*VS_ + v];
    float vm = acc * (1.0f/1024.0f);
    A0[(size_t)n*ASTR + 512 + v] = vm;
    A1[(size_t)n*ASTR + 512 + v] = vm;
  } else if (i < 16384 + 65536){        // A0 emb part = emb[tok0=0]
    int j = i - 16384; int n = j>>9, k = j&511;
    A0[(size_t)n*ASTR + k] = emb[k];
  } else if (i < 16384 + 2*65536){      // A0 h1 part = 0
    int j = i - 16384 - 65536; int n = j>>9, k = j&511;
    A0[(size_t)n*ASTR + 640 + k] = 0.0f;
  } else if (i < 16384 + 3*65536){      // c1 = 0
    C1[i - 16384 - 2*65536] = 0.0f;
  } else if (i < 16384 + 3*65536 + 16384){
    H2A[i - 16384 - 3*65536] = 0.0f;
  } else if (i < 16384 + 3*65536 + 2*16384){
    C2[i - 16384 - 3*65536 - 16384] = 0.0f;
  }
}

// ---- persistent decoder: 256 blocks x 256 threads, 3 grid barriers per step ----
__global__ __launch_bounds__(256, 1) void decoder_main(
  const float* __restrict__ key, const float* __restrict__ val,
  const int* __restrict__ lens, const float* __restrict__ emb,
  const float* __restrict__ W_ih1, const float* __restrict__ W_hh1,
  const float* __restrict__ b_ih1, const float* __restrict__ b_hh1,
  const float* __restrict__ W_ih2, const float* __restrict__ W_hh2,
  const float* __restrict__ b_ih2, const float* __restrict__ b_hh2,
  const float* __restrict__ W_out, const float* __restrict__ b_out,
  float* __restrict__ out, char* __restrict__ ws)
{
  __shared__ __align__(16) float smem[5504];   // A: As[16][68] + Ws[64][68]; C reuses
  float* As = smem;                     // 16*68 = 1088
  float* Ws = smem + 1088;              // 64*68 = 4352

  u32* cnt  = (u32*)ws;
  u32* flag = (u32*)(ws + 128);
  float* A0  = (float*)(ws + OFF_A0);
  float* A1  = (float*)(ws + OFF_A1);
  float* C1  = (float*)(ws + OFF_C1);
  float* H2A = (float*)(ws + OFF_H2A);
  float* H2B = (float*)(ws + OFF_H2B);
  float* C2  = (float*)(ws + OFF_C2);

  const int b = blockIdx.x;
  const int tid = threadIdx.x;

  float* Acur = A0; float* Anxt = A1;
  float* H2c = H2A; float* H2n = H2B;
  u32 ep = 0;

  #pragma unroll 1
  for (int step = 0; step < MAXLEN; ++step){
    // ================= Phase A: LSTM1 (all 256 blocks) =================
    // G[128 x 2048] (cols reordered c=4*hid+gate), K=1152. Tile 16 rows x 64 cols.
    {
      const int rt = b >> 5, ct = b & 31;
      const int row0 = rt*16, c0 = ct*64;
      const int wv_ = tid >> 6, lane = tid & 63;
      const int c_loc = (wv_<<4) + (lane & 15);    // wave w owns cols [16w,16w+16)
      const int r_slot = lane >> 4;                // rows {r,r+4,r+8,r+12}
      const int cgl = c0 + c_loc, chh = cgl>>2, cgg = cgl&3;
      const int c_st = tid >> 2, seg = tid & 3;    // staging: 4 threads/col-row, 16 f32 each
      const int sgl = c0 + c_st, shh = sgl>>2, sgg = sgl&3;
      const float* wsx = W_ih1 + (size_t)(sgg*H_ + shh)*640 + seg*16;
      const float* wsh = W_hh1 + (size_t)(sgg*H_ + shh)*512 + seg*16;
      const int r_st = tid >> 4, kq_st = tid & 15;
      const float* arow = Acur + (size_t)(row0 + r_st)*ASTR + kq_st*4;

      float acc0=0.f, acc1=0.f, acc2=0.f, acc3=0.f;
      float4 aR, w0, w1, w2, w3;
      w0 = ((const float4*)wsx)[0]; w1 = ((const float4*)wsx)[1];
      w2 = ((const float4*)wsx)[2]; w3 = ((const float4*)wsx)[3];
      aR = *(const float4*)arow;

      #pragma unroll 1
      for (int ch = 0; ch < 18; ++ch){
        __syncthreads();
        { float* wd = Ws + c_st*68 + seg*16;
          ((float4*)wd)[0]=w0; ((float4*)wd)[1]=w1; ((float4*)wd)[2]=w2; ((float4*)wd)[3]=w3;
          *(float4*)(As + r_st*68 + kq_st*4) = aR;
        }
        __syncthreads();
        if (ch < 17){
          int kb = (ch+1)*64;
          const float* p = (kb < 640) ? (wsx + kb) : (wsh + (kb-640));
          w0 = ((const float4*)p)[0]; w1 = ((const float4*)p)[1];
          w2 = ((const float4*)p)[2]; w3 = ((const float4*)p)[3];
          aR = *(const float4*)(arow + kb);
        }
        const float4* Wr = (const float4*)(Ws + c_loc*68);
        const float* Ap = As + r_slot*68;
        #pragma unroll
        for (int kq = 0; kq < 16; ++kq){
          float4 w  = Wr[kq];
          float4 a0 = *(const float4*)(Ap + kq*4);
          float4 a1 = *(const float4*)(Ap + 4*68 + kq*4);
          float4 a2 = *(const float4*)(Ap + 8*68 + kq*4);
          float4 a3 = *(const float4*)(Ap + 12*68 + kq*4);
          acc0 += dot4(a0,w); acc1 += dot4(a1,w); acc2 += dot4(a2,w); acc3 += dot4(a3,w);
        }
      }
      float bias = b_ih1[cgg*H_ + chh] + b_hh1[cgg*H_ + chh];
      __syncthreads();
      float* Gs = As;  // reuse [16][68]
      Gs[(r_slot   )*68 + c_loc] = acc0 + bias;
      Gs[(r_slot+ 4)*68 + c_loc] = acc1 + bias;
      Gs[(r_slot+ 8)*68 + c_loc] = acc2 + bias;
      Gs[(r_slot+12)*68 + c_loc] = acc3 + bias;
      __syncthreads();
      { const int r = tid >> 4, hl = tid & 15;
        float4 q = *(const float4*)(Gs + r*68 + hl*4);   // i,f,g,o
        const int row = row0 + r, hid = ct*16 + hl;
        float cold = C1[row*H_ + hid];
        float cn = sigf(q.y)*cold + sigf(q.x)*tanhf(q.z);
        float hn = sigf(q.w)*tanhf(cn);
        C1[row*H_ + hid] = cn;
        Anxt[(size_t)row*ASTR + 640 + hid] = hn;         // h1_s -> next A
      }
    }
    gbar(cnt, flag, ++ep);

    // ================= Phase B: LSTM2 (blocks 0..127) =================
    // G[128 x 512], K=640 = [h1_s(512) | h2_{s-1}(128)]. Tile 8 rows x 64 cols.
    if (b < 128){
      const int rt = b >> 3, ct = b & 7;
      const int row0 = rt*8, c0 = ct*64;
      const int wv_ = tid >> 6, lane = tid & 63;
      const int c_loc = (wv_<<4) + (lane & 15);
      const int r_slot = lane >> 4;                 // rows {r, r+4}
      const int cgl = c0 + c_loc, chh = cgl>>2, cgg = cgl&3;
      const int c_st = tid >> 2, seg = tid & 3;
      const int sgl = c0 + c_st, shh = sgl>>2, sgg = sgl&3;
      const float* wsx = W_ih2 + (size_t)(sgg*KS_ + shh)*H_  + seg*16;
      const float* wsh = W_hh2 + (size_t)(sgg*KS_ + shh)*KS_ + seg*16;
      const int r_st = tid >> 4, kq_st = tid & 15;

      float acc0=0.f, acc1=0.f;
      float4 aR, w0, w1, w2, w3;
      w0 = ((const float4*)wsx)[0]; w1 = ((const float4*)wsx)[1];
      w2 = ((const float4*)wsx)[2]; w3 = ((const float4*)wsx)[3];
      if (tid < 128) aR = *(const float4*)(Anxt + (size_t)(row0+r_st)*ASTR + 640 + kq_st*4);

      #pragma unroll 1
      for (int ch = 0; ch < 10; ++ch){
        __syncthreads();
        { float* wd = Ws + c_st*68 + seg*16;
          ((float4*)wd)[0]=w0; ((float4*)wd)[1]=w1; ((float4*)wd)[2]=w2; ((float4*)wd)[3]=w3;
          if (tid < 128) *(float4*)(As + r_st*68 + kq_st*4) = aR;
        }
        __syncthreads();
        if (ch < 9){
          int kb = (ch+1)*64;
          const float* p = (kb < 512) ? (wsx + kb) : (wsh + (kb-512));
          w0 = ((const float4*)p)[0]; w1 = ((const float4*)p)[1];
          w2 = ((const float4*)p)[2]; w3 = ((const float4*)p)[3];
          if (tid < 128){
            int k = kb + kq_st*4;
            aR = (kb < 512)
              ? *(const float4*)(Anxt + (size_t)(row0+r_st)*ASTR + 640 + k)
              : *(const float4*)(H2c  + (size_t)(row0+r_st)*KS_ + (k-512));
          }
        }
        const float4* Wr = (const float4*)(Ws + c_loc*68);
        #pragma unroll
        for (int kq = 0; kq < 16; ++kq){
          float4 w  = Wr[kq];
          float4 a0 = *(const float4*)(As + r_slot*68 + kq*4);
          float4 a1 = *(const float4*)(As + (r_slot+4)*68 + kq*4);
          acc0 += dot4(a0,w); acc1 += dot4(a1,w);
        }
      }
      float bias = b_ih2[cgg*KS_ + chh] + b_hh2[cgg*KS_ + chh];
      __syncthreads();
      float* Gs = As;
      Gs[(r_slot  )*68 + c_loc] = acc0 + bias;
      Gs[(r_slot+4)*68 + c_loc] = acc1 + bias;
      __syncthreads();
      if (tid < 128){
        const int r = tid >> 4, hl = tid & 15;
        float4 q = *(const float4*)(Gs + r*68 + hl*4);
        const int row = row0 + r, hid = ct*16 + hl;
        float cold = C2[row*KS_ + hid];
        float cn = sigf(q.y)*cold + sigf(q.x)*tanhf(q.z);
        float hn = sigf(q.w)*tanhf(cn);
        C2[row*KS_ + hid] = cn;
        H2n[row*KS_ + hid] = hn;
      }
    }
    gbar(cnt, flag, ++ep);

    // ===== Phase C: attention + out-proj + argmax + emb write (blocks 0..127) =====
    if (b < 128){
      const int n = b;
      float* Es  = smem;            // [1024] energies -> exp weights
      float* h2s = smem + 1024;     // [128]
      float* Zs  = smem + 1152;     // [256] = [h2 | ctx]
      float* Cs  = smem + 1408;     // [8][128] ctx partials
      float* red = smem + 2432;     // [256]
      float* Pr  = smem + 2688;     // [64] logits
      const int len = lens[n];
      if (tid < 128){ float v = H2n[n*KS_ + tid]; h2s[tid] = v; Zs[tid] = v; }
      __syncthreads();
      for (int t0 = 0; t0 < 4; ++t0){
        int t = t0*256 + tid;
        if (t < len){
          const float4* kp = (const float4*)(key + ((size_t)t*N_ + n)*KS_);
          float e = 0.f;
          #pragma unroll
          for (int k4 = 0; k4 < 32; ++k4){
            float4 q = kp[k4];
            e += q.x*h2s[k4*4+0] + q.y*h2s[k4*4+1] + q.z*h2s[k4*4+2] + q.w*h2s[k4*4+3];
          }
          Es[t] = e;
        }
      }
      __syncthreads();
      float lm = -3.0e38f;
      for (int t = tid; t < len; t += 256) lm = fmaxf(lm, Es[t]);
      red[tid] = lm; __syncthreads();
      for (int s2 = 128; s2 > 0; s2 >>= 1){ if (tid < s2) red[tid] = fmaxf(red[tid], red[tid+s2]); __syncthreads(); }
      const float m = red[0];
      __syncthreads();
      float ls = 0.f;
      for (int t = tid; t < len; t += 256){ float p = expf(Es[t]-m); Es[t] = p; ls += p; }
      red[tid] = ls; __syncthreads();
      for (int s2 = 128; s2 > 0; s2 >>= 1){ if (tid < s2) red[tid] += red[tid+s2]; __syncthreads(); }
      const float inv = 1.0f / red[0];
      __syncthreads();
      // ctx: thread = (part 0..7, v4) 8-way t-split, float4 in v
      const int part = tid >> 5, v4 = (tid & 31)*4;
      float cA=0.f,cB=0.f,cC=0.f,cD=0.f;
      for (int t = part; t < len; t += 8){
        float p = Es[t];
        float4 u = *(const float4*)(val + ((size_t)t*N_ + n)*VS_ + v4);
        cA += p*u.x; cB += p*u.y; cC += p*u.z; cD += p*u.w;
      }
      Cs[part*128 + v4+0]=cA; Cs[part*128 + v4+1]=cB; Cs[part*128 + v4+2]=cC; Cs[part*128 + v4+3]=cD;
      __syncthreads();
      if (tid < 128){
        float s = 0.f;
        #pragma unroll
        for (int p8 = 0; p8 < 8; ++p8) s += Cs[p8*128 + tid];
        Zs[128 + tid] = s * inv;
      }
      __syncthreads();
      if (tid < V_){
        const float4* wr = (const float4*)(W_out + tid*256);
        float a = b_out[tid];
        #pragma unroll
        for (int k4 = 0; k4 < 64; ++k4){
          float4 q = wr[k4];
          a += q.x*Zs[k4*4+0] + q.y*Zs[k4*4+1] + q.z*Zs[k4*4+2] + q.w*Zs[k4*4+3];
        }
        Pr[tid] = a;
        out[((size_t)n*MAXLEN + step)*V_ + tid] = a;
      }
      __syncthreads();
      if (tid == 0){
        float bm = Pr[0]; int bi = 0;
        for (int v2 = 1; v2 < V_; ++v2){ float pv = Pr[v2]; if (pv > bm){ bm = pv; bi = v2; } }
        ((int*)red)[0] = bi;
      }
      __syncthreads();
      const int tok = ((int*)red)[0];
      Anxt[(size_t)n*ASTR + tid]       = emb[(size_t)tok*H_ + tid];
      Anxt[(size_t)n*ASTR + 256 + tid] = emb[(size_t)tok*H_ + 256 + tid];
    }
    gbar(cnt, flag, ++ep);

    // swap ping-pong buffers
    float* tp = Acur; Acur = Anxt; Anxt = tp;
    tp = H2c; H2c = H2n; H2n = tp;
  }
}

extern "C" void kernel_launch(void* const* d_in, const int* in_sizes, int n_in,
                              void* d_out, int out_size, void* d_ws, size_t ws_size,
                              hipStream_t stream)
{
  const float* key    = (const float*)d_in[0];
  const float* val    = (const float*)d_in[1];
  const int*   lens   = (const int*)d_in[2];
  const float* emb    = (const float*)d_in[3];
  const float* W_ih1  = (const float*)d_in[4];
  const float* W_hh1  = (const float*)d_in[5];
  const float* b_ih1  = (const float*)d_in[6];
  const float* b_hh1  = (const float*)d_in[7];
  const float* W_ih2  = (const float*)d_in[8];
  const float* W_hh2  = (const float*)d_in[9];
  const float* b_ih2  = (const float*)d_in[10];
  const float* b_hh2  = (const float*)d_in[11];
  const float* W_out  = (const float*)d_in[12];
  const float* b_out  = (const float*)d_in[13];

  (void)in_sizes; (void)n_in; (void)out_size; (void)ws_size;

  hipMemsetAsync(d_ws, 0, 256, stream);                     // barrier cnt/flag
  prep_state<<<960, 256, 0, stream>>>(val, emb, (char*)d_ws);
  decoder_main<<<NBLK, 256, 0, stream>>>(
      key, val, lens, emb, W_ih1, W_hh1, b_ih1, b_hh1,
      W_ih2, W_hh2, b_ih2, b_hh2, W_out, b_out,
      (float*)d_out, (char*)d_ws);
}

// Round 3
// 29567.377 us; speedup vs baseline: 3.1205x; 3.1205x over previous
//
#include <hip/hip_runtime.h>
#include <math.h>

typedef unsigned int u32;

#define T_     1024
#define N_     128
#define V_     35
#define H_     512
#define VS_    128
#define KS_    128
#define MAXLEN 250
#define NBLK   256
#define ASTR   1152   // A row: [emb(512) | vm(128) | h1(512)]

// ---- workspace layout (bytes) ----
// [0,512): spare | [512): bcast flag | [1024, 17408): 256 arrival slots, 64B apart
#define OFF_FLAG  512
#define OFF_SLOTS 1024
#define OFF_A0    36864
#define SZ_A    (N_*ASTR*4)          // 589824
#define OFF_A1  (OFF_A0+SZ_A)
#define OFF_C1  (OFF_A1+SZ_A)
#define SZ_C1   (N_*H_*4)            // 262144
#define OFF_H2A (OFF_C1+SZ_C1)
#define SZ_H2   (N_*KS_*4)           // 65536
#define OFF_H2B (OFF_H2A+SZ_H2)
#define OFF_C2  (OFF_H2B+SZ_H2)
// total ~1.68 MB

__device__ __forceinline__ float sigf(float x){ return 1.0f/(1.0f+expf(-x)); }
__device__ __forceinline__ float dot4(float4 a, float4 b){ return a.x*b.x + a.y*b.y + a.z*b.z + a.w*b.w; }

// Two-level flag barrier: per-block arrival slots (64B apart, plain release
// stores, no RMW), block 0 aggregates with 256 parallel relaxed polls, then
// broadcasts. ONE __threadfence per block per barrier (vs one invalidate per
// poll iteration in the round-2 version, which caused the 114us/barrier +
// 10 GB of L2 refill traffic).
__device__ __forceinline__ void gbar(u32* slots, u32* bflag, u32 ep, int b){
  __syncthreads();
  if (threadIdx.x == 0){
    __threadfence();   // release: publish this block's writes
    __hip_atomic_store(&slots[(size_t)b*16], ep, __ATOMIC_RELAXED, __HIP_MEMORY_SCOPE_AGENT);
  }
  if (b == 0){
    u32* ms = &slots[(size_t)threadIdx.x*16];
    while (__hip_atomic_load(ms, __ATOMIC_RELAXED, __HIP_MEMORY_SCOPE_AGENT) < ep)
      __builtin_amdgcn_s_sleep(1);
    __syncthreads();
    if (threadIdx.x == 0){
      __threadfence(); // acquire (for block 0's own reads) + release for chain
      __hip_atomic_store(bflag, ep, __ATOMIC_RELAXED, __HIP_MEMORY_SCOPE_AGENT);
    }
  } else {
    if (threadIdx.x == 0){
      while (__hip_atomic_load(bflag, __ATOMIC_RELAXED, __HIP_MEMORY_SCOPE_AGENT) < ep)
        __builtin_amdgcn_s_sleep(2);
      __threadfence(); // acquire: invalidate stale lines once
    }
  }
  __syncthreads();
}

// ---- one-time prep: one block per batch row n ----
__global__ void prep_state(const float* __restrict__ val, const float* __restrict__ emb, char* __restrict__ ws){
  __shared__ float part[256];
  float* A0  = (float*)(ws + OFF_A0);
  float* A1  = (float*)(ws + OFF_A1);
  float* C1  = (float*)(ws + OFF_C1);
  float* H2A = (float*)(ws + OFF_H2A);
  float* C2  = (float*)(ws + OFF_C2);
  const int n = blockIdx.x, tid = threadIdx.x;
  const int c = tid >> 7, v = tid & 127;
  float acc = 0.f;
  const float* vp = val + (size_t)(c*512)*N_*VS_ + (size_t)n*VS_ + v;
  #pragma unroll 8
  for (int t = 0; t < 512; ++t) acc += vp[(size_t)t*N_*VS_];
  part[tid] = acc;
  __syncthreads();
  if (tid < 128){
    float vm = (part[tid] + part[tid+128]) * (1.0f/1024.0f);
    A0[(size_t)n*ASTR + 512 + tid] = vm;
    A1[(size_t)n*ASTR + 512 + tid] = vm;
    H2A[n*KS_ + tid] = 0.f;
    C2 [n*KS_ + tid] = 0.f;
  }
  A0[(size_t)n*ASTR + tid]       = emb[tid];        // emb[tok0=0]
  A0[(size_t)n*ASTR + 256 + tid] = emb[256 + tid];
  A0[(size_t)n*ASTR + 640 + tid] = 0.f;             // h1 = 0
  A0[(size_t)n*ASTR + 896 + tid] = 0.f;
  C1[(size_t)n*H_ + tid]       = 0.f;
  C1[(size_t)n*H_ + 256 + tid] = 0.f;
}

// ---- persistent decoder: 256 blocks x 256 threads, 3 grid barriers per step ----
__global__ __launch_bounds__(256, 1) void decoder_main(
  const float* __restrict__ key, const float* __restrict__ val,
  const int* __restrict__ lens, const float* __restrict__ emb,
  const float* __restrict__ W_ih1, const float* __restrict__ W_hh1,
  const float* __restrict__ b_ih1, const float* __restrict__ b_hh1,
  const float* __restrict__ W_ih2, const float* __restrict__ W_hh2,
  const float* __restrict__ b_ih2, const float* __restrict__ b_hh2,
  const float* __restrict__ W_out, const float* __restrict__ b_out,
  float* __restrict__ out, char* __restrict__ ws)
{
  __shared__ __align__(16) float smem[5504];   // A: As[16][68] + Ws[64][68]; C reuses
  float* As = smem;                     // 16*68 = 1088
  float* Ws = smem + 1088;              // 64*68 = 4352

  u32* bflag = (u32*)(ws + OFF_FLAG);
  u32* slots = (u32*)(ws + OFF_SLOTS);
  float* A0  = (float*)(ws + OFF_A0);
  float* A1  = (float*)(ws + OFF_A1);
  float* C1  = (float*)(ws + OFF_C1);
  float* H2A = (float*)(ws + OFF_H2A);
  float* H2B = (float*)(ws + OFF_H2B);
  float* C2  = (float*)(ws + OFF_C2);

  const int b = blockIdx.x;
  const int tid = threadIdx.x;

  float* Acur = A0; float* Anxt = A1;
  float* H2c = H2A; float* H2n = H2B;
  u32 ep = 0;

  #pragma unroll 1
  for (int step = 0; step < MAXLEN; ++step){
    // ================= Phase A: LSTM1 (all 256 blocks) =================
    // G[128 x 2048] (cols reordered c=4*hid+gate), K=1152. Tile 16 rows x 64 cols.
    {
      const int rt = b >> 5, ct = b & 31;
      const int row0 = rt*16, c0 = ct*64;
      const int wv_ = tid >> 6, lane = tid & 63;
      const int c_loc = (wv_<<4) + (lane & 15);    // wave w owns cols [16w,16w+16)
      const int r_slot = lane >> 4;                // rows {r,r+4,r+8,r+12}
      const int cgl = c0 + c_loc, chh = cgl>>2, cgg = cgl&3;
      const int c_st = tid >> 2, seg = tid & 3;    // staging: 4 threads/col-row, 16 f32 each
      const int sgl = c0 + c_st, shh = sgl>>2, sgg = sgl&3;
      const float* wsx = W_ih1 + (size_t)(sgg*H_ + shh)*640 + seg*16;
      const float* wsh = W_hh1 + (size_t)(sgg*H_ + shh)*512 + seg*16;
      const int r_st = tid >> 4, kq_st = tid & 15;
      const float* arow = Acur + (size_t)(row0 + r_st)*ASTR + kq_st*4;

      float acc0=0.f, acc1=0.f, acc2=0.f, acc3=0.f;
      float4 aR, w0, w1, w2, w3;
      w0 = ((const float4*)wsx)[0]; w1 = ((const float4*)wsx)[1];
      w2 = ((const float4*)wsx)[2]; w3 = ((const float4*)wsx)[3];
      aR = *(const float4*)arow;

      #pragma unroll 1
      for (int ch = 0; ch < 18; ++ch){
        __syncthreads();
        { float* wd = Ws + c_st*68 + seg*16;
          ((float4*)wd)[0]=w0; ((float4*)wd)[1]=w1; ((float4*)wd)[2]=w2; ((float4*)wd)[3]=w3;
          *(float4*)(As + r_st*68 + kq_st*4) = aR;
        }
        __syncthreads();
        if (ch < 17){
          int kb = (ch+1)*64;
          const float* p = (kb < 640) ? (wsx + kb) : (wsh + (kb-640));
          w0 = ((const float4*)p)[0]; w1 = ((const float4*)p)[1];
          w2 = ((const float4*)p)[2]; w3 = ((const float4*)p)[3];
          aR = *(const float4*)(arow + kb);
        }
        const float4* Wr = (const float4*)(Ws + c_loc*68);
        const float* Ap = As + r_slot*68;
        #pragma unroll
        for (int kq = 0; kq < 16; ++kq){
          float4 w  = Wr[kq];
          float4 a0 = *(const float4*)(Ap + kq*4);
          float4 a1 = *(const float4*)(Ap + 4*68 + kq*4);
          float4 a2 = *(const float4*)(Ap + 8*68 + kq*4);
          float4 a3 = *(const float4*)(Ap + 12*68 + kq*4);
          acc0 += dot4(a0,w); acc1 += dot4(a1,w); acc2 += dot4(a2,w); acc3 += dot4(a3,w);
        }
      }
      float bias = b_ih1[cgg*H_ + chh] + b_hh1[cgg*H_ + chh];
      __syncthreads();
      float* Gs = As;  // reuse [16][68]
      Gs[(r_slot   )*68 + c_loc] = acc0 + bias;
      Gs[(r_slot+ 4)*68 + c_loc] = acc1 + bias;
      Gs[(r_slot+ 8)*68 + c_loc] = acc2 + bias;
      Gs[(r_slot+12)*68 + c_loc] = acc3 + bias;
      __syncthreads();
      { const int r = tid >> 4, hl = tid & 15;
        float4 q = *(const float4*)(Gs + r*68 + hl*4);   // i,f,g,o
        const int row = row0 + r, hid = ct*16 + hl;
        float cold = C1[row*H_ + hid];
        float cn = sigf(q.y)*cold + sigf(q.x)*tanhf(q.z);
        float hn = sigf(q.w)*tanhf(cn);
        C1[row*H_ + hid] = cn;
        Anxt[(size_t)row*ASTR + 640 + hid] = hn;         // h1_s -> next A
      }
    }
    gbar(slots, bflag, ++ep, b);

    // ================= Phase B: LSTM2 (blocks 0..127) =================
    // G[128 x 512], K=640 = [h1_s(512) | h2_{s-1}(128)]. Tile 8 rows x 64 cols.
    if (b < 128){
      const int rt = b >> 3, ct = b & 7;
      const int row0 = rt*8, c0 = ct*64;
      const int wv_ = tid >> 6, lane = tid & 63;
      const int c_loc = (wv_<<4) + (lane & 15);
      const int r_slot = lane >> 4;                 // rows {r, r+4}
      const int cgl = c0 + c_loc, chh = cgl>>2, cgg = cgl&3;
      const int c_st = tid >> 2, seg = tid & 3;
      const int sgl = c0 + c_st, shh = sgl>>2, sgg = sgl&3;
      const float* wsx = W_ih2 + (size_t)(sgg*KS_ + shh)*H_  + seg*16;
      const float* wsh = W_hh2 + (size_t)(sgg*KS_ + shh)*KS_ + seg*16;
      const int r_st = tid >> 4, kq_st = tid & 15;

      float acc0=0.f, acc1=0.f;
      float4 aR, w0, w1, w2, w3;
      w0 = ((const float4*)wsx)[0]; w1 = ((const float4*)wsx)[1];
      w2 = ((const float4*)wsx)[2]; w3 = ((const float4*)wsx)[3];
      if (tid < 128) aR = *(const float4*)(Anxt + (size_t)(row0+r_st)*ASTR + 640 + kq_st*4);

      #pragma unroll 1
      for (int ch = 0; ch < 10; ++ch){
        __syncthreads();
        { float* wd = Ws + c_st*68 + seg*16;
          ((float4*)wd)[0]=w0; ((float4*)wd)[1]=w1; ((float4*)wd)[2]=w2; ((float4*)wd)[3]=w3;
          if (tid < 128) *(float4*)(As + r_st*68 + kq_st*4) = aR;
        }
        __syncthreads();
        if (ch < 9){
          int kb = (ch+1)*64;
          const float* p = (kb < 512) ? (wsx + kb) : (wsh + (kb-512));
          w0 = ((const float4*)p)[0]; w1 = ((const float4*)p)[1];
          w2 = ((const float4*)p)[2]; w3 = ((const float4*)p)[3];
          if (tid < 128){
            int k = kb + kq_st*4;
            aR = (kb < 512)
              ? *(const float4*)(Anxt + (size_t)(row0+r_st)*ASTR + 640 + k)
              : *(const float4*)(H2c  + (size_t)(row0+r_st)*KS_ + (k-512));
          }
        }
        const float4* Wr = (const float4*)(Ws + c_loc*68);
        #pragma unroll
        for (int kq = 0; kq < 16; ++kq){
          float4 w  = Wr[kq];
          float4 a0 = *(const float4*)(As + r_slot*68 + kq*4);
          float4 a1 = *(const float4*)(As + (r_slot+4)*68 + kq*4);
          acc0 += dot4(a0,w); acc1 += dot4(a1,w);
        }
      }
      float bias = b_ih2[cgg*KS_ + chh] + b_hh2[cgg*KS_ + chh];
      __syncthreads();
      float* Gs = As;
      Gs[(r_slot  )*68 + c_loc] = acc0 + bias;
      Gs[(r_slot+4)*68 + c_loc] = acc1 + bias;
      __syncthreads();
      if (tid < 128){
        const int r = tid >> 4, hl = tid & 15;
        float4 q = *(const float4*)(Gs + r*68 + hl*4);
        const int row = row0 + r, hid = ct*16 + hl;
        float cold = C2[row*KS_ + hid];
        float cn = sigf(q.y)*cold + sigf(q.x)*tanhf(q.z);
        float hn = sigf(q.w)*tanhf(cn);
        C2[row*KS_ + hid] = cn;
        H2n[row*KS_ + hid] = hn;
      }
    }
    gbar(slots, bflag, ++ep, b);

    // ===== Phase C: attention + out-proj + argmax + emb write (blocks 0..127) =====
    if (b < 128){
      const int n = b;
      float* Es  = smem;            // [1024] energies -> exp weights
      float* h2s = smem + 1024;     // [128]
      float* Zs  = smem + 1152;     // [256] = [h2 | ctx]
      float* Cs  = smem + 1408;     // [8][128] ctx partials
      float* red = smem + 2432;     // [256]
      float* Pr  = smem + 2688;     // [64] logits
      const int len = lens[n];
      if (tid < 128){ float v = H2n[n*KS_ + tid]; h2s[tid] = v; Zs[tid] = v; }
      __syncthreads();
      for (int t0 = 0; t0 < 4; ++t0){
        int t = t0*256 + tid;
        if (t < len){
          const float4* kp = (const float4*)(key + ((size_t)t*N_ + n)*KS_);
          float e = 0.f;
          #pragma unroll
          for (int k4 = 0; k4 < 32; ++k4){
            float4 q = kp[k4];
            e += q.x*h2s[k4*4+0] + q.y*h2s[k4*4+1] + q.z*h2s[k4*4+2] + q.w*h2s[k4*4+3];
          }
          Es[t] = e;
        }
      }
      __syncthreads();
      float lm = -3.0e38f;
      for (int t = tid; t < len; t += 256) lm = fmaxf(lm, Es[t]);
      red[tid] = lm; __syncthreads();
      for (int s2 = 128; s2 > 0; s2 >>= 1){ if (tid < s2) red[tid] = fmaxf(red[tid], red[tid+s2]); __syncthreads(); }
      const float m = red[0];
      __syncthreads();
      float ls = 0.f;
      for (int t = tid; t < len; t += 256){ float p = expf(Es[t]-m); Es[t] = p; ls += p; }
      red[tid] = ls; __syncthreads();
      for (int s2 = 128; s2 > 0; s2 >>= 1){ if (tid < s2) red[tid] += red[tid+s2]; __syncthreads(); }
      const float inv = 1.0f / red[0];
      __syncthreads();
      // ctx: thread = (part 0..7, v4) 8-way t-split, float4 in v
      const int part = tid >> 5, v4 = (tid & 31)*4;
      float cA=0.f,cB=0.f,cC=0.f,cD=0.f;
      for (int t = part; t < len; t += 8){
        float p = Es[t];
        float4 u = *(const float4*)(val + ((size_t)t*N_ + n)*VS_ + v4);
        cA += p*u.x; cB += p*u.y; cC += p*u.z; cD += p*u.w;
      }
      Cs[part*128 + v4+0]=cA; Cs[part*128 + v4+1]=cB; Cs[part*128 + v4+2]=cC; Cs[part*128 + v4+3]=cD;
      __syncthreads();
      if (tid < 128){
        float s = 0.f;
        #pragma unroll
        for (int p8 = 0; p8 < 8; ++p8) s += Cs[p8*128 + tid];
        Zs[128 + tid] = s * inv;
      }
      __syncthreads();
      if (tid < V_){
        const float4* wr = (const float4*)(W_out + tid*256);
        float a = b_out[tid];
        #pragma unroll
        for (int k4 = 0; k4 < 64; ++k4){
          float4 q = wr[k4];
          a += q.x*Zs[k4*4+0] + q.y*Zs[k4*4+1] + q.z*Zs[k4*4+2] + q.w*Zs[k4*4+3];
        }
        Pr[tid] = a;
        out[((size_t)n*MAXLEN + step)*V_ + tid] = a;
      }
      __syncthreads();
      if (tid == 0){
        float bm = Pr[0]; int bi = 0;
        for (int v2 = 1; v2 < V_; ++v2){ float pv = Pr[v2]; if (pv > bm){ bm = pv; bi = v2; } }
        ((int*)red)[0] = bi;
      }
      __syncthreads();
      const int tok = ((int*)red)[0];
      Anxt[(size_t)n*ASTR + tid]       = emb[(size_t)tok*H_ + tid];
      Anxt[(size_t)n*ASTR + 256 + tid] = emb[(size_t)tok*H_ + 256 + tid];
    }
    gbar(slots, bflag, ++ep, b);

    // swap ping-pong buffers
    float* tp = Acur; Acur = Anxt; Anxt = tp;
    tp = H2c; H2c = H2n; H2n = tp;
  }
}

extern "C" void kernel_launch(void* const* d_in, const int* in_sizes, int n_in,
                              void* d_out, int out_size, void* d_ws, size_t ws_size,
                              hipStream_t stream)
{
  const float* key    = (const float*)d_in[0];
  const float* val    = (const float*)d_in[1];
  const int*   lens   = (const int*)d_in[2];
  const float* emb    = (const float*)d_in[3];
  const float* W_ih1  = (const float*)d_in[4];
  const float* W_hh1  = (const float*)d_in[5];
  const float* b_ih1  = (const float*)d_in[6];
  const float* b_hh1  = (const float*)d_in[7];
  const float* W_ih2  = (const float*)d_in[8];
  const float* W_hh2  = (const float*)d_in[9];
  const float* b_ih2  = (const float*)d_in[10];
  const float* b_hh2  = (const float*)d_in[11];
  const float* W_out  = (const float*)d_in[12];
  const float* b_out  = (const float*)d_in[13];

  (void)in_sizes; (void)n_in; (void)out_size; (void)ws_size;

  hipMemsetAsync(d_ws, 0, OFF_A0, stream);   // barrier slots + flag
  prep_state<<<128, 256, 0, stream>>>(val, emb, (char*)d_ws);
  decoder_main<<<NBLK, 256, 0, stream>>>(
      key, val, lens, emb, W_ih1, W_hh1, b_ih1, b_hh1,
      W_ih2, W_hh2, b_ih2, b_hh2, W_out, b_out,
      (float*)d_out, (char*)d_ws);
}